// Round 20
// baseline (106.210 us; speedup 1.0000x reference)
//
#include <hip/hip_runtime.h>
#include <stdint.h>

typedef __attribute__((ext_vector_type(4))) int   i32x4v;
typedef __attribute__((ext_vector_type(16))) int  i32x16v;
typedef __attribute__((ext_vector_type(4))) float f32x4;

#define PIX 3136            // 56*56
#define WW 56
#define SPL 53824           // sub-plane: 58*58*16 B
#define SLAB 215296         // one (n,cc64) slab = 4 sub-planes
#define APL 5184            // LDS bytes per A sub-plane (>=5120 DMA span;
                            //  1296 dwords == 16 mod 32 banks -> halves de-aliased)
#define ABUFSZ 20736        // one A buffer: 4 * APL
#define ABASE 24576         // A dbuf base (B triple-buf below)
#define EPQ (32*69*4)       // epilogue per-wave quadrant: 8832 B
#define LDSB 66048          // B 3x8192 + A 2x20736; epilogue 35328 overlays

// workspace (bytes): two sub-planar i8 tensors + transposed weights + flag
#define XBP_BYTES ((size_t)32*4*215296)           // 27,557,888
#define OFF_XBP2  (XBP_BYTES)
#define OFF_WBT   (2*XBP_BYTES)
#define WBT_BYTES ((size_t)9*16*256*16)           // 589,824
#define OFF_FLAG  (OFF_WBT + WBT_BYTES)
#define WS_NEED   (OFF_FLAG + 64)

// Fused prologue: block 0 = flag; blocks 1..256 = halo-zero; 257.. = w repack.
__global__ __launch_bounds__(256) void k_prep(
    const float* __restrict__ s1, const float* __restrict__ s2,
    const float* __restrict__ w, char* __restrict__ ws,
    char* __restrict__ wbTt, int* __restrict__ flag) {
    int b = blockIdx.x;
    int t = threadIdx.x;
    if (b == 0) {
        __shared__ int bad;
        if (t == 0) bad = 0;
        __syncthreads();
        if (s1[t] != s2[t]) atomicAdd(&bad, 1);
        __syncthreads();
        if (t == 0) *flag = (bad == 0) ? 1 : 0;
        return;
    }
    if (b <= 256) {
        // halo ring of one slab, sub-planar: 4 sub-planes x 228 16B-units
        char* base = ws + (size_t)(b - 1) * SLAB;
        int4 z = {0, 0, 0, 0};
#pragma unroll
        for (int i = 0; i < 4; ++i) {
            int u = t + i * 256;
            if (u >= 912) break;
            int s = u / 228, v = u - s * 228;
            int off;
            if (v < 58)       off = v;                       // top row
            else if (v < 116) off = 3306 + (v - 58);         // bottom row (57*58)
            else { int r = v - 116; off = ((r >> 1) + 1) * 58 + (r & 1) * 57; }
            *(int4*)(base + s * SPL + off * 16) = z;
        }
        return;
    }
    int idx = (b - 257) * 256 + t;               // 0..589823
    int kk = idx >> 16;
    int sub = (idx >> 12) & 15;
    int oc = (idx >> 4) & 255;
    int lo = idx & 15;
    float v = w[(oc * 256 + sub * 16 + lo) * 9 + kk];
    wbTt[idx] = (v > 0.f) ? (char)1 : ((v < 0.f) ? (char)-1 : (char)0);
}

// NCHW fp32 -> sub-planar halo-padded i8: xbp[n][cc][sub][py][px][16B] = sign(x+shift)
__global__ __launch_bounds__(256) void k_repack_x(
    const float* __restrict__ x, const float* __restrict__ sh1,
    const float* __restrict__ sh2, char* __restrict__ xbp1,
    char* __restrict__ xbp2, const int* __restrict__ flag) {
    __shared__ float lds[64 * 68];
    bool eq = (*flag != 0);
    int t = threadIdx.x;
    int b = blockIdx.x;
    int n = b / 49;
    int p0 = (b % 49) * 64;

    int pixw = t >> 2;
    int sub  = t & 3;
    int pw = p0 + pixw;
    int yw = pw / WW, xw = pw % WW;

    int cl = t >> 4;
    int p4 = (t & 15) * 4;

    for (int cc = 0; cc < 256; cc += 64) {
        __syncthreads();
#pragma unroll
        for (int i = 0; i < 4; ++i) {
            float4 v = *(const float4*)(x + (size_t)(n * 256 + cc + cl + i * 16) * PIX + p0 + p4);
            *(float4*)(&lds[(cl + i * 16) * 68 + p4]) = v;
        }
        __syncthreads();
        size_t obase = (size_t)(n * 4 + (cc >> 6)) * SLAB + (size_t)sub * SPL
                     + ((size_t)(yw + 1) * 58 + (xw + 1)) * 16;
        union { char c[16]; int4 v; } u1, u2;
#pragma unroll
        for (int k = 0; k < 16; ++k) {
            int c = sub * 16 + k;
            float v = lds[c * 68 + pixw];
            float a1 = v + sh1[cc + c];
            float a2 = v + sh2[cc + c];
            u1.c[k] = (a1 > 0.f) ? (char)1 : ((a1 < 0.f) ? (char)-1 : (char)0);
            u2.c[k] = (a2 > 0.f) ? (char)1 : ((a2 < 0.f) ? (char)-1 : (char)0);
        }
        *(int4*)(xbp1 + obase) = u1.v;
        if (!eq) *(int4*)(xbp2 + obase) = u2.v;
    }
}

// Implicit-GEMM binary conv, i8 MFMA. r19 geometry (tile 128px x 128oc, 4 waves,
// wave 64x64, acc 64 AGPR) + T4 COUNTED-VMCNT pipeline (m201 discipline):
//   B TRIPLE-buffered, stage for tap t+2 issued at tap t -> ~2 taps of cover;
//   per-tap publication = asm "s_waitcnt vmcnt(N)" (N>0, NEVER drain-to-0 in
//   the main loop) -> __builtin_amdgcn_s_barrier() -> sched_barrier(0).
//   A DOUBLE-buffered, staged at (cc,4). Exact in-order vmcnt queue accounting
//   (per-wave issue order B(s+2) then A): N=7 at s in {4,5,13,14,22,23}
//   (A's 5 loads + next B's 2 behind the wait), N=0 at s=34 (no s+2 stage),
//   else N=2 (leave B(s+2) in flight).
// r13/r14 raced with a FUSED asm barrier and no sched_barrier; m201's trio is
// the HW-verified publication idiom for counted LDS-DMA pipelines on gfx950.
// T5 setprio(1) wraps the MFMA cluster. LDS 66KB -> 2 blocks/CU (occupancy
// proven non-binding in r19).
// MODE 0: EQ: out=(acc+b)*(1+w1). MODE 1: out=acc+(1+w1)b. MODE 2: out+=w1*acc.
template <int MODE>
__global__ __launch_bounds__(256, 4) void k_bgemm(
    const char* __restrict__ xsrc, const char* __restrict__ wbTt,
    const float* __restrict__ bias, const float* __restrict__ w1,
    const int* __restrict__ flag, float* __restrict__ out) {
    bool eq = (*flag != 0);
    if (MODE == 0 ? !eq : eq) return;    // block-uniform

    __shared__ char lds[LDSB];

    const int t = threadIdx.x;
    const int l = t & 63, wid = t >> 6;
    const int wc = wid & 1;
    const int r32 = l & 31, half = l >> 5;
    const int l16 = l * 16;

    // XCD-chunked swizzle: 1600 = 8*200; ntile fastest -> both oc-tiles of a
    // window on one XCD (A L2-shared); adjacent tp share window rows.
    const int logical = (blockIdx.x & 7) * 200 + (blockIdx.x >> 3);
    const int ntile = logical & 1;
    const int m = logical >> 1;          // 0..799
    const int n = m / 25, tp = m % 25;
    const int p0 = tp * 128;             // tp=24: half-valid tile
    const int y0 = p0 / WW;
    const int y0c = (y0 < 53) ? y0 : 53; // 5-row window rows y0c..y0c+4 (<=57)
    const int pxb = p0 + (wid >> 1) * 64;    // wave's pixel base

    int wpm[2];
#pragma unroll
    for (int mi = 0; mi < 2; ++mi) {
        int g = pxb + mi * 32 + r32;
        if (g > 3135) g = 3135;          // only in store-disabled waves
        int yg = g / WW, xg = g - yg * WW;
        wpm[mi] = (yg + 1 - y0c) * 58 + xg + 1;  // 16B-unit index in plane
    }

    // stage one 8KB B tile (cc,kk, this block's 128 oc) -> B buffer t2%3
    // layout [ci4][oc128][16B]; wave w stages ci=w (2 x 1KB DMAs)
    auto stageB = [&](int t2) {                  // t2 compile-time
        const int cc2 = t2 / 9, kk2 = t2 % 9;
        const char* src = wbTt
            + ((size_t)((kk2 * 16 + cc2 * 4 + wid) * 256 + ntile * 128)) * 16 + l16;
        char* dst = lds + (t2 % 3) * 8192 + wid * 2048;
#pragma unroll
        for (int j = 0; j < 2; ++j)
            __builtin_amdgcn_global_load_lds(
                (const __attribute__((address_space(1))) void*)(src + j * 1024),
                (__attribute__((address_space(3))) void*)(dst + j * 1024), 16, 0, 0);
    };
    // stage A window into buffer par (4 sub-planes x 5 rows; wave w stages plane
    // w, 5 x 1KB DMAs; over-stages 480B/plane into the APL pad - benign)
    auto stageA = [&](int par, int cc2) {
        const char* src = xsrc + (size_t)(n * 4 + cc2) * SLAB + (size_t)wid * SPL
                        + y0c * 928 + l16;
        char* dst = lds + ABASE + par * ABUFSZ + wid * APL;
#pragma unroll
        for (int j = 0; j < 5; ++j)
            __builtin_amdgcn_global_load_lds(
                (const __attribute__((address_space(1))) void*)(src + j * 1024),
                (__attribute__((address_space(3))) void*)(dst + j * 1024), 16, 0, 0);
    };

    i32x16v acc[2][2];                   // [mi][nj]
#pragma unroll
    for (int mi = 0; mi < 2; ++mi)
#pragma unroll
        for (int nj = 0; nj < 2; ++nj)
#pragma unroll
            for (int i = 0; i < 16; ++i) acc[mi][nj][i] = 0;

    // prologue: A(0)->buf0 [5], B(0) [2], B(1) [2]; need A(0),B(0) retired,
    // B(1) may stay in flight -> vmcnt(2); publish via the m201 trio.
    stageA(0, 0);
    stageB(0);
    stageB(1);
    asm volatile("s_waitcnt vmcnt(2)" ::: "memory");
    __builtin_amdgcn_s_barrier();
    __builtin_amdgcn_sched_barrier(0);

#pragma unroll
    for (int cc = 0; cc < 4; ++cc) {
#pragma unroll
        for (int kk = 0; kk < 9; ++kk) {
            const int tix = cc * 9 + kk;
            // issue-early: B for tap t+2 (into the third buffer)
            if (tix + 2 <= 35) stageB(tix + 2);
            // A for cc+1 issued at (cc,4), AFTER this tap's B issue (queue order)
            if (kk == 4 && cc < 3) stageA((cc + 1) & 1, cc + 1);
            const int ts = (kk / 3 - 1) * 58 + (kk % 3) - 1;
            const char* Ab = lds + ABASE + (cc & 1) * ABUFSZ;
            const char* Bb = lds + (tix % 3) * 8192;
            __builtin_amdgcn_s_setprio(1);
#pragma unroll
            for (int kq = 0; kq < 2; ++kq) {
                const int ci = kq * 2 + half;
                i32x4v af0 = *(const i32x4v*)(Ab + ci * APL + (wpm[0] + ts) * 16);
                i32x4v af1 = *(const i32x4v*)(Ab + ci * APL + (wpm[1] + ts) * 16);
                i32x4v bf0 = *(const i32x4v*)(Bb + ci * 2048 + (wc * 64 + r32) * 16);
                i32x4v bf1 = *(const i32x4v*)(Bb + ci * 2048 + (wc * 64 + 32 + r32) * 16);
                acc[0][0] = __builtin_amdgcn_mfma_i32_32x32x32_i8(af0, bf0, acc[0][0], 0, 0, 0);
                acc[0][1] = __builtin_amdgcn_mfma_i32_32x32x32_i8(af0, bf1, acc[0][1], 0, 0, 0);
                acc[1][0] = __builtin_amdgcn_mfma_i32_32x32x32_i8(af1, bf0, acc[1][0], 0, 0, 0);
                acc[1][1] = __builtin_amdgcn_mfma_i32_32x32x32_i8(af1, bf1, acc[1][1], 0, 0, 0);
            }
            __builtin_amdgcn_s_setprio(0);
            if (tix < 35) {
                // counted publication: retire everything up to B(tix+1)
                // (and A when queued behind the wait); leave newer loads flying.
                if (tix == 4 || tix == 5 || tix == 13 || tix == 14 ||
                    tix == 22 || tix == 23) {
                    asm volatile("s_waitcnt vmcnt(7)" ::: "memory");
                } else if (tix == 34) {
                    asm volatile("s_waitcnt vmcnt(0)" ::: "memory");
                } else {
                    asm volatile("s_waitcnt vmcnt(2)" ::: "memory");
                }
                __builtin_amdgcn_s_barrier();
                __builtin_amdgcn_sched_barrier(0);
            }
        }
    }

    // ---- epilogue: wave-private LDS transpose quadrant -> 256B nt stores ----
    __syncthreads();                     // full drain; buffers dead -> quadrants
    const int ocb = ntile * 128 + wc * 64;
    const bool pvalid = pxb < PIX;
    float w1v = w1[0];
    float se = 1.f + w1v;
    float* sb = (float*)(lds + wid * EPQ);   // [32 oc][69 px]
    size_t outb = (size_t)n * 256 * PIX + pxb;

#pragma unroll
    for (int nj = 0; nj < 2; ++nj) {
        float bv = bias[ocb + nj * 32 + r32];
#pragma unroll
        for (int mi = 0; mi < 2; ++mi)
#pragma unroll
            for (int q = 0; q < 4; ++q) {
                f32x4 v;
#pragma unroll
                for (int j = 0; j < 4; ++j) {
                    float a = (float)(acc[mi][nj][q * 4 + j]);
                    if (MODE == 0)      v[j] = (a + bv) * se;
                    else if (MODE == 1) v[j] = a + se * bv;
                    else                v[j] = w1v * a;
                }
                *(f32x4*)(sb + r32 * 69 + mi * 32 + q * 8 + half * 4) = v;
            }
        asm volatile("s_waitcnt lgkmcnt(0)" ::: "memory");
        if (pvalid) {
#pragma unroll
            for (int p = 0; p < 8; ++p) {
                int row = p * 4 + (l >> 4);          // oc-rel 0..31
                int px4 = (l & 15) * 4;              // 0..60
                f32x4 v = *(const f32x4*)(sb + row * 69 + px4);
                float* op = out + outb + (size_t)(ocb + nj * 32 + row) * PIX + px4;
                if (MODE == 2) {
                    f32x4 o = *(const f32x4*)op;
                    v[0] += o[0]; v[1] += o[1]; v[2] += o[2]; v[3] += o[3];
                }
                __builtin_nontemporal_store(v, (f32x4*)op);
            }
        }
        if (nj == 0) asm volatile("s_waitcnt lgkmcnt(0)" ::: "memory");
    }
}

extern "C" void kernel_launch(void* const* d_in, const int* in_sizes, int n_in,
                              void* d_out, int out_size, void* d_ws, size_t ws_size,
                              hipStream_t stream) {
    const float* x    = (const float*)d_in[0];
    const float* sh1  = (const float*)d_in[1];
    const float* sh2  = (const float*)d_in[2];
    const float* wgt  = (const float*)d_in[3];
    const float* bias = (const float*)d_in[4];
    const float* w1   = (const float*)d_in[5];
    float* out = (float*)d_out;
    char* ws = (char*)d_ws;
    if (ws_size < WS_NEED) return;

    char* xbp1 = ws;
    char* xbp2 = ws + OFF_XBP2;
    char* wbTt = ws + OFF_WBT;
    int* flag  = (int*)(ws + OFF_FLAG);

    k_prep<<<2561, 256, 0, stream>>>(sh1, sh2, wgt, ws, wbTt, flag);
    k_repack_x<<<32 * 49, 256, 0, stream>>>(x, sh1, sh2, xbp1, xbp2, flag);
    k_bgemm<0><<<1600, 256, 0, stream>>>(xbp1, wbTt, bias, w1, flag, out);
    k_bgemm<1><<<1600, 256, 0, stream>>>(xbp1, wbTt, bias, w1, flag, out);
    k_bgemm<2><<<1600, 256, 0, stream>>>(xbp2, wbTt, bias, w1, flag, out);
}

// Round 23
// 101.545 us; speedup vs baseline: 1.0459x; 1.0459x over previous
//
#include <hip/hip_runtime.h>
#include <stdint.h>

typedef __attribute__((ext_vector_type(4))) int   i32x4v;
typedef __attribute__((ext_vector_type(16))) int  i32x16v;
typedef __attribute__((ext_vector_type(4))) float f32x4;

#define PIX 3136            // 56*56
#define WW 56
#define SPL 53824           // sub-plane: 58*58*16 B
#define SLAB 215296         // one (n,cc64) slab = 4 sub-planes
#define APL 5184            // LDS bytes per A sub-plane (>=5120 DMA span;
                            //  1296 dwords == 16 mod 32 banks -> halves de-aliased)
#define ABASE 16384         // A window base (B dbuf below it)
#define EPQ (32*69*4)       // epilogue per-wave quadrant: 8832 B
#define LDSB 37120          // B dbuf 16384 + A 20736; epilogue 35328 overlays

// workspace (bytes): two sub-planar i8 tensors + transposed weights + flag
#define XBP_BYTES ((size_t)32*4*215296)           // 27,557,888
#define OFF_XBP2  (XBP_BYTES)
#define OFF_WBT   (2*XBP_BYTES)
#define WBT_BYTES ((size_t)9*16*256*16)           // 589,824
#define OFF_FLAG  (OFF_WBT + WBT_BYTES)
#define WS_NEED   (OFF_FLAG + 64)

// Fused prologue: block 0 = flag; blocks 1..256 = halo-zero; 257.. = w repack.
__global__ __launch_bounds__(256) void k_prep(
    const float* __restrict__ s1, const float* __restrict__ s2,
    const float* __restrict__ w, char* __restrict__ ws,
    char* __restrict__ wbTt, int* __restrict__ flag) {
    int b = blockIdx.x;
    int t = threadIdx.x;
    if (b == 0) {
        __shared__ int bad;
        if (t == 0) bad = 0;
        __syncthreads();
        if (s1[t] != s2[t]) atomicAdd(&bad, 1);
        __syncthreads();
        if (t == 0) *flag = (bad == 0) ? 1 : 0;
        return;
    }
    if (b <= 256) {
        // halo ring of one slab, sub-planar: 4 sub-planes x 228 16B-units
        char* base = ws + (size_t)(b - 1) * SLAB;
        int4 z = {0, 0, 0, 0};
#pragma unroll
        for (int i = 0; i < 4; ++i) {
            int u = t + i * 256;
            if (u >= 912) break;
            int s = u / 228, v = u - s * 228;
            int off;
            if (v < 58)       off = v;                       // top row
            else if (v < 116) off = 3306 + (v - 58);         // bottom row (57*58)
            else { int r = v - 116; off = ((r >> 1) + 1) * 58 + (r & 1) * 57; }
            *(int4*)(base + s * SPL + off * 16) = z;
        }
        return;
    }
    int idx = (b - 257) * 256 + t;               // 0..589823
    int kk = idx >> 16;
    int sub = (idx >> 12) & 15;
    int oc = (idx >> 4) & 255;
    int lo = idx & 15;
    float v = w[(oc * 256 + sub * 16 + lo) * 9 + kk];
    wbTt[idx] = (v > 0.f) ? (char)1 : ((v < 0.f) ? (char)-1 : (char)0);
}

// NCHW fp32 -> sub-planar halo-padded i8: xbp[n][cc][sub][py][px][16B] = sign(x+shift)
__global__ __launch_bounds__(256) void k_repack_x(
    const float* __restrict__ x, const float* __restrict__ sh1,
    const float* __restrict__ sh2, char* __restrict__ xbp1,
    char* __restrict__ xbp2, const int* __restrict__ flag) {
    __shared__ float lds[64 * 68];
    bool eq = (*flag != 0);
    int t = threadIdx.x;
    int b = blockIdx.x;
    int n = b / 49;
    int p0 = (b % 49) * 64;

    int pixw = t >> 2;
    int sub  = t & 3;
    int pw = p0 + pixw;
    int yw = pw / WW, xw = pw % WW;

    int cl = t >> 4;
    int p4 = (t & 15) * 4;

    for (int cc = 0; cc < 256; cc += 64) {
        __syncthreads();
#pragma unroll
        for (int i = 0; i < 4; ++i) {
            float4 v = *(const float4*)(x + (size_t)(n * 256 + cc + cl + i * 16) * PIX + p0 + p4);
            *(float4*)(&lds[(cl + i * 16) * 68 + p4]) = v;
        }
        __syncthreads();
        size_t obase = (size_t)(n * 4 + (cc >> 6)) * SLAB + (size_t)sub * SPL
                     + ((size_t)(yw + 1) * 58 + (xw + 1)) * 16;
        union { char c[16]; int4 v; } u1, u2;
#pragma unroll
        for (int k = 0; k < 16; ++k) {
            int c = sub * 16 + k;
            float v = lds[c * 68 + pixw];
            float a1 = v + sh1[cc + c];
            float a2 = v + sh2[cc + c];
            u1.c[k] = (a1 > 0.f) ? (char)1 : ((a1 < 0.f) ? (char)-1 : (char)0);
            u2.c[k] = (a2 > 0.f) ? (char)1 : ((a2 < 0.f) ? (char)-1 : (char)0);
        }
        *(int4*)(xbp1 + obase) = u1.v;
        if (!eq) *(int4*)(xbp2 + obase) = u2.v;
    }
}

// Implicit-GEMM binary conv, i8 MFMA. EXACT r19 structure (session best, 80.3us):
// tile 128px x 128oc, 4 waves (2px x 2oc), wave 64x64, acc 64 AGPR, B 8KB/tap
// dbuf + A window single-buf restaged per cc, per-tap __syncthreads publication
// (the ONLY publication idiom that passed every round; counted-vmcnt without a
// real barrier failed 4x: r13/14/21/22 -> vmcnt retirement alone is not a safe
// consume signal for LDS-DMA on this toolchain).
// DISPATCH FUSION (this round): old MODE0/MODE1 unified -- both read xbp1 and
// differ only in epilogue: EQ (a+bv)*se == a*se + se*bv; NEQ a + se*bv.
// Unified: v = a*s1 + se*bv, s1 = eq ? se : 1 (runtime flag, block-uniform,
// no early-exit dispatch). Second pass k_bgemm_add (out += w1*acc on xbp2)
// runs only when !eq.
__global__ __launch_bounds__(256, 4) void k_bgemm_main(
    const char* __restrict__ xsrc, const char* __restrict__ wbTt,
    const float* __restrict__ bias, const float* __restrict__ w1,
    const int* __restrict__ flag, float* __restrict__ out) {
    bool eq = (*flag != 0);

    __shared__ char lds[LDSB];

    const int t = threadIdx.x;
    const int l = t & 63, wid = t >> 6;
    const int wc = wid & 1;
    const int r32 = l & 31, half = l >> 5;
    const int l16 = l * 16;

    // XCD-chunked swizzle: 1600 = 8*200; ntile fastest -> both oc-tiles of a
    // window on one XCD (A L2-shared); adjacent tp share window rows.
    const int logical = (blockIdx.x & 7) * 200 + (blockIdx.x >> 3);
    const int ntile = logical & 1;
    const int m = logical >> 1;          // 0..799
    const int n = m / 25, tp = m % 25;
    const int p0 = tp * 128;             // tp=24: half-valid tile
    const int y0 = p0 / WW;
    const int y0c = (y0 < 53) ? y0 : 53; // 5-row window rows y0c..y0c+4 (<=57)
    const int pxb = p0 + (wid >> 1) * 64;    // wave's pixel base

    int wpm[2];
#pragma unroll
    for (int mi = 0; mi < 2; ++mi) {
        int g = pxb + mi * 32 + r32;
        if (g > 3135) g = 3135;          // only in store-disabled waves
        int yg = g / WW, xg = g - yg * WW;
        wpm[mi] = (yg + 1 - y0c) * 58 + xg + 1;  // 16B-unit index in plane
    }

    // stage one 8KB B tile (cc,kk, this block's 128 oc) -> Bbuf[par]
    // layout [ci4][oc128][16B]; wave w stages ci=w (2 x 1KB DMAs)
    auto stageB = [&](int par, int t2) {         // t2 compile-time
        const int cc2 = t2 / 9, kk2 = t2 % 9;
        const char* src = wbTt
            + ((size_t)((kk2 * 16 + cc2 * 4 + wid) * 256 + ntile * 128)) * 16 + l16;
        char* dst = lds + par * 8192 + wid * 2048;
#pragma unroll
        for (int j = 0; j < 2; ++j)
            __builtin_amdgcn_global_load_lds(
                (const __attribute__((address_space(1))) void*)(src + j * 1024),
                (__attribute__((address_space(3))) void*)(dst + j * 1024), 16, 0, 0);
    };
    // stage A window (4 sub-planes x 5 rows; wave w stages plane w, 5 x 1KB DMAs;
    // over-stages 480B/plane into the APL pad - benign)
    auto stageA = [&](int cc2) {
        const char* src = xsrc + (size_t)(n * 4 + cc2) * SLAB + (size_t)wid * SPL
                        + y0c * 928 + l16;
        char* dst = lds + ABASE + wid * APL;
#pragma unroll
        for (int j = 0; j < 5; ++j)
            __builtin_amdgcn_global_load_lds(
                (const __attribute__((address_space(1))) void*)(src + j * 1024),
                (__attribute__((address_space(3))) void*)(dst + j * 1024), 16, 0, 0);
    };

    i32x16v acc[2][2];                   // [mi][nj]
#pragma unroll
    for (int mi = 0; mi < 2; ++mi)
#pragma unroll
        for (int nj = 0; nj < 2; ++nj)
#pragma unroll
            for (int i = 0; i < 16; ++i) acc[mi][nj][i] = 0;

    // prologue: A(cc=0) + B(tap 0), publish (full-counter drain - m97 idiom)
    stageA(0);
    stageB(0, 0);
    __syncthreads();

#pragma unroll
    for (int cc = 0; cc < 4; ++cc) {
#pragma unroll
        for (int kk = 0; kk < 9; ++kk) {
            const int tix = cc * 9 + kk;
            if (tix < 35) stageB((tix + 1) & 1, tix + 1);    // issue-early
            const int ts = (kk / 3 - 1) * 58 + (kk % 3) - 1;
            const char* Ab = lds + ABASE;
            const char* Bb = lds + (tix & 1) * 8192;
#pragma unroll
            for (int kq = 0; kq < 2; ++kq) {
                const int ci = kq * 2 + half;
                i32x4v af0 = *(const i32x4v*)(Ab + ci * APL + (wpm[0] + ts) * 16);
                i32x4v af1 = *(const i32x4v*)(Ab + ci * APL + (wpm[1] + ts) * 16);
                i32x4v bf0 = *(const i32x4v*)(Bb + ci * 2048 + (wc * 64 + r32) * 16);
                i32x4v bf1 = *(const i32x4v*)(Bb + ci * 2048 + (wc * 64 + 32 + r32) * 16);
                acc[0][0] = __builtin_amdgcn_mfma_i32_32x32x32_i8(af0, bf0, acc[0][0], 0, 0, 0);
                acc[0][1] = __builtin_amdgcn_mfma_i32_32x32x32_i8(af0, bf1, acc[0][1], 0, 0, 0);
                acc[1][0] = __builtin_amdgcn_mfma_i32_32x32x32_i8(af1, bf0, acc[1][0], 0, 0, 0);
                acc[1][1] = __builtin_amdgcn_mfma_i32_32x32x32_i8(af1, bf1, acc[1][1], 0, 0, 0);
            }
            __syncthreads();             // publish t+1's B; readers of tap t done
        }
        // cc boundary: A readers done (last sync above) -> restage A, publish
        if (cc < 3) {
            stageA(cc + 1);
            __syncthreads();
        }
    }

    // ---- epilogue: wave-private LDS transpose quadrant -> 256B nt stores ----
    // unified formula: v = a*s1 + se*bv; s1 = eq ? se : 1  (EQ: (a+bv)*se;
    // NEQ pass 1: a + se*bv -- pass 2 adds w1*acc2)
    const int ocb = ntile * 128 + wc * 64;
    const bool pvalid = pxb < PIX;
    float w1v = w1[0];
    float se = 1.f + w1v;
    float s1 = eq ? se : 1.f;
    float* sb = (float*)(lds + wid * EPQ);   // [32 oc][69 px]
    size_t outb = (size_t)n * 256 * PIX + pxb;

#pragma unroll
    for (int nj = 0; nj < 2; ++nj) {
        float bb = se * bias[ocb + nj * 32 + r32];
#pragma unroll
        for (int mi = 0; mi < 2; ++mi)
#pragma unroll
            for (int q = 0; q < 4; ++q) {
                f32x4 v;
#pragma unroll
                for (int j = 0; j < 4; ++j)
                    v[j] = (float)(acc[mi][nj][q * 4 + j]) * s1 + bb;
                *(f32x4*)(sb + r32 * 69 + mi * 32 + q * 8 + half * 4) = v;
            }
        asm volatile("s_waitcnt lgkmcnt(0)" ::: "memory");
        if (pvalid) {
#pragma unroll
            for (int p = 0; p < 8; ++p) {
                int row = p * 4 + (l >> 4);          // oc-rel 0..31
                int px4 = (l & 15) * 4;              // 0..60
                f32x4 v = *(const f32x4*)(sb + row * 69 + px4);
                float* op = out + outb + (size_t)(ocb + nj * 32 + row) * PIX + px4;
                __builtin_nontemporal_store(v, (f32x4*)op);
            }
        }
        if (nj == 0) asm volatile("s_waitcnt lgkmcnt(0)" ::: "memory");
    }
}

// Second pass (only when shifts differ): out += w1 * conv(xbp2). Early exit
// when EQ (block-uniform, before any barrier).
__global__ __launch_bounds__(256, 4) void k_bgemm_add(
    const char* __restrict__ xsrc, const char* __restrict__ wbTt,
    const float* __restrict__ bias, const float* __restrict__ w1,
    const int* __restrict__ flag, float* __restrict__ out) {
    if (*flag != 0) return;              // EQ: nothing to add

    __shared__ char lds[LDSB];

    const int t = threadIdx.x;
    const int l = t & 63, wid = t >> 6;
    const int wc = wid & 1;
    const int r32 = l & 31, half = l >> 5;
    const int l16 = l * 16;

    const int logical = (blockIdx.x & 7) * 200 + (blockIdx.x >> 3);
    const int ntile = logical & 1;
    const int m = logical >> 1;
    const int n = m / 25, tp = m % 25;
    const int p0 = tp * 128;
    const int y0 = p0 / WW;
    const int y0c = (y0 < 53) ? y0 : 53;
    const int pxb = p0 + (wid >> 1) * 64;

    int wpm[2];
#pragma unroll
    for (int mi = 0; mi < 2; ++mi) {
        int g = pxb + mi * 32 + r32;
        if (g > 3135) g = 3135;
        int yg = g / WW, xg = g - yg * WW;
        wpm[mi] = (yg + 1 - y0c) * 58 + xg + 1;
    }

    auto stageB = [&](int par, int t2) {
        const int cc2 = t2 / 9, kk2 = t2 % 9;
        const char* src = wbTt
            + ((size_t)((kk2 * 16 + cc2 * 4 + wid) * 256 + ntile * 128)) * 16 + l16;
        char* dst = lds + par * 8192 + wid * 2048;
#pragma unroll
        for (int j = 0; j < 2; ++j)
            __builtin_amdgcn_global_load_lds(
                (const __attribute__((address_space(1))) void*)(src + j * 1024),
                (__attribute__((address_space(3))) void*)(dst + j * 1024), 16, 0, 0);
    };
    auto stageA = [&](int cc2) {
        const char* src = xsrc + (size_t)(n * 4 + cc2) * SLAB + (size_t)wid * SPL
                        + y0c * 928 + l16;
        char* dst = lds + ABASE + wid * APL;
#pragma unroll
        for (int j = 0; j < 5; ++j)
            __builtin_amdgcn_global_load_lds(
                (const __attribute__((address_space(1))) void*)(src + j * 1024),
                (__attribute__((address_space(3))) void*)(dst + j * 1024), 16, 0, 0);
    };

    i32x16v acc[2][2];
#pragma unroll
    for (int mi = 0; mi < 2; ++mi)
#pragma unroll
        for (int nj = 0; nj < 2; ++nj)
#pragma unroll
            for (int i = 0; i < 16; ++i) acc[mi][nj][i] = 0;

    stageA(0);
    stageB(0, 0);
    __syncthreads();

#pragma unroll
    for (int cc = 0; cc < 4; ++cc) {
#pragma unroll
        for (int kk = 0; kk < 9; ++kk) {
            const int tix = cc * 9 + kk;
            if (tix < 35) stageB((tix + 1) & 1, tix + 1);
            const int ts = (kk / 3 - 1) * 58 + (kk % 3) - 1;
            const char* Ab = lds + ABASE;
            const char* Bb = lds + (tix & 1) * 8192;
#pragma unroll
            for (int kq = 0; kq < 2; ++kq) {
                const int ci = kq * 2 + half;
                i32x4v af0 = *(const i32x4v*)(Ab + ci * APL + (wpm[0] + ts) * 16);
                i32x4v af1 = *(const i32x4v*)(Ab + ci * APL + (wpm[1] + ts) * 16);
                i32x4v bf0 = *(const i32x4v*)(Bb + ci * 2048 + (wc * 64 + r32) * 16);
                i32x4v bf1 = *(const i32x4v*)(Bb + ci * 2048 + (wc * 64 + 32 + r32) * 16);
                acc[0][0] = __builtin_amdgcn_mfma_i32_32x32x32_i8(af0, bf0, acc[0][0], 0, 0, 0);
                acc[0][1] = __builtin_amdgcn_mfma_i32_32x32x32_i8(af0, bf1, acc[0][1], 0, 0, 0);
                acc[1][0] = __builtin_amdgcn_mfma_i32_32x32x32_i8(af1, bf0, acc[1][0], 0, 0, 0);
                acc[1][1] = __builtin_amdgcn_mfma_i32_32x32x32_i8(af1, bf1, acc[1][1], 0, 0, 0);
            }
            __syncthreads();
        }
        if (cc < 3) {
            stageA(cc + 1);
            __syncthreads();
        }
    }

    const int ocb = ntile * 128 + wc * 64;
    const bool pvalid = pxb < PIX;
    float w1v = w1[0];
    float* sb = (float*)(lds + wid * EPQ);
    size_t outb = (size_t)n * 256 * PIX + pxb;

#pragma unroll
    for (int nj = 0; nj < 2; ++nj) {
#pragma unroll
        for (int mi = 0; mi < 2; ++mi)
#pragma unroll
            for (int q = 0; q < 4; ++q) {
                f32x4 v;
#pragma unroll
                for (int j = 0; j < 4; ++j)
                    v[j] = w1v * (float)(acc[mi][nj][q * 4 + j]);
                *(f32x4*)(sb + r32 * 69 + mi * 32 + q * 8 + half * 4) = v;
            }
        asm volatile("s_waitcnt lgkmcnt(0)" ::: "memory");
        if (pvalid) {
#pragma unroll
            for (int p = 0; p < 8; ++p) {
                int row = p * 4 + (l >> 4);
                int px4 = (l & 15) * 4;
                f32x4 v = *(const f32x4*)(sb + row * 69 + px4);
                float* op = out + outb + (size_t)(ocb + nj * 32 + row) * PIX + px4;
                f32x4 o = *(const f32x4*)op;
                v[0] += o[0]; v[1] += o[1]; v[2] += o[2]; v[3] += o[3];
                __builtin_nontemporal_store(v, (f32x4*)op);
            }
        }
        if (nj == 0) asm volatile("s_waitcnt lgkmcnt(0)" ::: "memory");
    }
}

extern "C" void kernel_launch(void* const* d_in, const int* in_sizes, int n_in,
                              void* d_out, int out_size, void* d_ws, size_t ws_size,
                              hipStream_t stream) {
    const float* x    = (const float*)d_in[0];
    const float* sh1  = (const float*)d_in[1];
    const float* sh2  = (const float*)d_in[2];
    const float* wgt  = (const float*)d_in[3];
    const float* bias = (const float*)d_in[4];
    const float* w1   = (const float*)d_in[5];
    float* out = (float*)d_out;
    char* ws = (char*)d_ws;
    if (ws_size < WS_NEED) return;

    char* xbp1 = ws;
    char* xbp2 = ws + OFF_XBP2;
    char* wbTt = ws + OFF_WBT;
    int* flag  = (int*)(ws + OFF_FLAG);

    k_prep<<<2561, 256, 0, stream>>>(sh1, sh2, wgt, ws, wbTt, flag);
    k_repack_x<<<32 * 49, 256, 0, stream>>>(x, sh1, sh2, xbp1, xbp2, flag);
    k_bgemm_main<<<1600, 256, 0, stream>>>(xbp1, wbTt, bias, w1, flag, out);
    k_bgemm_add<<<1600, 256, 0, stream>>>(xbp2, wbTt, bias, w1, flag, out);
}